// Round 6
// baseline (462.213 us; speedup 1.0000x reference)
//
#include <hip/hip_runtime.h>

#define NPG  256   // nodes per graph
#define EPG  4096  // edges per graph
#define FDIM 128
#define KTOP 30
#define NT   512   // 8 waves, 2/SIMD
#define RS   36    // row stride (floats): 16B-aligned AND bank-even for b128
#define ZROW 256   // zero pad row (degree-divergence padding)

// amdgpu_waves_per_eu(2,2): pin min=max=2 waves/EU -> VGPR budget exactly 256.
// Rounds 3-5 showed __launch_bounds__' 2nd arg is only a MINIMUM occupancy
// (VGPR ceiling the compiler may undershoot): the spill heuristic picked
// 64/128 VGPR and spilled ~900MB/launch of gather state to scratch.
__global__ __attribute__((amdgpu_waves_per_eu(2, 2))) __launch_bounds__(NT)
void dgcnn_fused(const float* __restrict__ node_feat,
                 const int* __restrict__ srcv, const int* __restrict__ dstv,
                 const int* __restrict__ degs,
                 const float* __restrict__ W0, const float* __restrict__ b0,
                 const float* __restrict__ W1, const float* __restrict__ b1,
                 const float* __restrict__ W2, const float* __restrict__ b2,
                 const float* __restrict__ W3, const float* __restrict__ b3,
                 const float* __restrict__ cw1, const float* __restrict__ cb1,
                 const float* __restrict__ cw2, const float* __restrict__ cb2,
                 const float* __restrict__ ow,  const float* __restrict__ ob,
                 float* __restrict__ outp)
{
    __shared__ __attribute__((aligned(16))) float Buf[(NPG + 1) * RS]; // 37008 B
    __shared__ unsigned short srclist[EPG];  // 8192 B; in-edges grouped by dst
    __shared__ int   offs[NPG];
    __shared__ int   cnt [NPG];
    __shared__ int   degl[NPG];
    __shared__ float invd[NPG];
    __shared__ float keys[NPG];
    __shared__ float sbuf[NPG];
    __shared__ int   rnk [NPG];
    // total ~52.3 KB

    const int g = blockIdx.x;
    const int t = threadIdx.x;

    // ================= degrees + exclusive scan =================
    if (t < NPG) {
        int dn = degs[g * NPG + t];
        degl[t] = dn; cnt[t] = 0;
        invd[t] = 1.0f / (float)(dn + 1);
        offs[t] = dn;
    }
    __syncthreads();
    for (int s = 1; s < NPG; s <<= 1) {
        int v = 0;
        if (t < NPG && t >= s) v = offs[t - s];
        __syncthreads();
        if (t < NPG) offs[t] += v;
        __syncthreads();
    }
    if (t < NPG) offs[t] -= degl[t];   // exclusive prefix
    if (t < RS) Buf[ZROW * RS + t] = 0.f;   // zero pad row
    __syncthreads();

    // ================= edge-list build (counting sort by dst) =================
    {
        const int4* sg4 = (const int4*)(srcv + g * EPG);
        const int4* dg4 = (const int4*)(dstv + g * EPG);
        #pragma unroll
        for (int i = 0; i < 2; i++) {
            int4 s4 = sg4[t + i * NT];
            int4 d4 = dg4[t + i * NT];
            int ss[4] = {s4.x, s4.y, s4.z, s4.w};
            int dd[4] = {d4.x, d4.y, d4.z, d4.w};
            #pragma unroll
            for (int u = 0; u < 4; u++) {
                int sl = ss[u] & (NPG - 1);
                int dl = dd[u] & (NPG - 1);
                int p  = atomicAdd(&cnt[dl], 1);
                srclist[offs[dl] + p] = (unsigned short)sl;
            }
        }
    }

    // thread roles
    const int n  = t & (NPG - 1);   // matmul mapping: node
    const int hh = t >> 8;          // 0/1: channel half
    const int cb = hh << 4;         // channel base (0 or 16)
    const int c4  = (t & 7) << 2;   // gather mapping: 4-ch base (0..28)
    const int grp = t >> 3;         // 0..63 node quad
    const int nb  = grp << 2;       // first node of quad

    int   go[4], gd[4];
    float giv[4];
    #pragma unroll
    for (int i = 0; i < 4; i++) { go[i] = offs[nb + i]; gd[i] = degl[nb + i]; giv[i] = invd[nb + i]; }
    int dm = max(max(gd[0], gd[1]), max(gd[2], gd[3]));

    // ================= phase 0: y0 = X @ W0 (thread = (n,hh): 16 out-ch) ======
    float acc[16];
    #pragma unroll
    for (int c = 0; c < 16; c++) acc[c] = 0.f;
    {
        const float* nf = node_feat + (size_t)g * NPG * FDIM;
        for (int kc = 0; kc < 4; kc++) {
            __syncthreads();   // Buf chunk reuse
            #pragma unroll
            for (int i = 0; i < 4; i++) {
                int f  = t + i * NT;          // 0..2047
                int nn = f >> 3, k4 = f & 7;
                float4 v = *(const float4*)(nf + nn * FDIM + kc * 32 + k4 * 4);
                *(float4*)(&Buf[nn * RS + k4 * 4]) = v;   // bank-even b128
            }
            __syncthreads();
            // 16-float chunks: keeps live row regs ~16 (round-5's row[32] fed
            // the spill heuristic)
            #pragma unroll
            for (int half = 0; half < 2; half++) {
                float r[16];
                #pragma unroll
                for (int j = 0; j < 4; j++) {
                    float4 v = *(const float4*)(&Buf[n * RS + half * 16 + j * 4]);
                    r[j*4+0] = v.x; r[j*4+1] = v.y; r[j*4+2] = v.z; r[j*4+3] = v.w;
                }
                const float* wb = W0 + (kc * 32 + half * 16) * 32 + cb;
                #pragma unroll
                for (int k = 0; k < 16; k++) {
                    float hk = r[k];
                    const float* wr = wb + k * 32;   // wave-uniform -> scalar loads
                    #pragma unroll
                    for (int c = 0; c < 16; c++) acc[c] = fmaf(hk, wr[c], acc[c]);
                }
            }
        }
    }
    __syncthreads();
    #pragma unroll
    for (int u = 0; u < 4; u++) {
        float4 v = {acc[u*4], acc[u*4+1], acc[u*4+2], acc[u*4+3]};
        *(float4*)(&Buf[n * RS + cb + u * 4]) = v;   // y0
    }
    __syncthreads();

    // pooled quad gather: pool[i] = Buf[nb+i] + sum_edges Buf[src]  (4 ch/lane)
    auto gather = [&](float4 (&pool)[4]) {
        #pragma unroll
        for (int i = 0; i < 4; i++)
            pool[i] = *(const float4*)(&Buf[(nb + i) * RS + c4]);   // self
        for (int j = 0; j < dm; j++) {
            #pragma unroll
            for (int i = 0; i < 4; i++) {
                int a = ZROW;
                if (j < gd[i]) a = (int)srclist[go[i] + j];   // 8-lane broadcast
                float4 r = *(const float4*)(&Buf[a * RS + c4]);  // bank-even b128
                pool[i].x += r.x; pool[i].y += r.y;
                pool[i].z += r.z; pool[i].w += r.w;
            }
        }
    };

    // ---- layer 0: pooled(y0) -> h1 (computed in gather mapping) ----
    {
        float4 p[4];
        gather(p);
        float4 bv = *(const float4*)(b0 + c4);
        __syncthreads();   // all gather reads of y0 done
        #pragma unroll
        for (int i = 0; i < 4; i++) {
            float4 hv;
            hv.x = tanhf((p[i].x + bv.x) * giv[i]);
            hv.y = tanhf((p[i].y + bv.y) * giv[i]);
            hv.z = tanhf((p[i].z + bv.z) * giv[i]);
            hv.w = tanhf((p[i].w + bv.w) * giv[i]);
            *(float4*)(&Buf[(nb + i) * RS + c4]) = hv;   // h1
        }
        __syncthreads();
    }

    float a1[16], a2[16], a3[16];   // Z archive in (n,hh) layout

    // capture a1 = h1[n][cb..cb+15] while it's still in Buf
    #pragma unroll
    for (int j = 0; j < 4; j++) {
        float4 v = *(const float4*)(&Buf[n * RS + cb + j * 4]);
        a1[j*4+0] = v.x; a1[j*4+1] = v.y; a1[j*4+2] = v.z; a1[j*4+3] = v.w;
    }

    // ---- layers 1,2: gather pooled -> write -> matmul+tanh -> write ----
    auto layer = [&](const float* Wn, const float* bn, float (&ar)[16]) {
        float4 p[4];
        gather(p);
        __syncthreads();   // all gather reads done
        #pragma unroll
        for (int i = 0; i < 4; i++)
            *(float4*)(&Buf[(nb + i) * RS + c4]) = p[i];   // pooled rows
        __syncthreads();
        float y[16];
        #pragma unroll
        for (int c = 0; c < 16; c++) y[c] = 0.f;
        #pragma unroll
        for (int half = 0; half < 2; half++) {
            float r[16];
            #pragma unroll
            for (int j = 0; j < 4; j++) {
                float4 v = *(const float4*)(&Buf[n * RS + half * 16 + j * 4]);
                r[j*4+0] = v.x; r[j*4+1] = v.y; r[j*4+2] = v.z; r[j*4+3] = v.w;
            }
            const float* wb = Wn + (half * 16) * 32 + cb;
            #pragma unroll
            for (int k = 0; k < 16; k++) {
                float pk = r[k];
                const float* wr = wb + k * 32;   // wave-uniform -> scalar loads
                #pragma unroll
                for (int c = 0; c < 16; c++) y[c] = fmaf(pk, wr[c], y[c]);
            }
        }
        float ivn = invd[n];
        #pragma unroll
        for (int c = 0; c < 16; c++) ar[c] = tanhf((y[c] + bn[cb + c]) * ivn);
        __syncthreads();   // all pooled-row reads done
        #pragma unroll
        for (int u = 0; u < 4; u++) {
            float4 v = {ar[u*4], ar[u*4+1], ar[u*4+2], ar[u*4+3]};
            *(float4*)(&Buf[n * RS + cb + u * 4]) = v;   // h_next
        }
        __syncthreads();
    };
    layer(W1, b1, a2);
    layer(W2, b2, a3);

    // ---- layer 3: project h3 -> scalar (linearity), pool scalars -> keys ----
    if (t < NPG) {
        float s = 0.f;
        #pragma unroll
        for (int j = 0; j < 8; j++) {
            float4 v = *(const float4*)(&Buf[t * RS + j * 4]);
            s = fmaf(v.x, W3[j*4+0], s); s = fmaf(v.y, W3[j*4+1], s);
            s = fmaf(v.z, W3[j*4+2], s); s = fmaf(v.w, W3[j*4+3], s);
        }
        sbuf[t] = s;
    }
    __syncthreads();
    if (t < NPG) {
        float s = sbuf[t];
        int oo = offs[t], d2 = degl[t];
        for (int j = 0; j < d2; j++) s += sbuf[srclist[oo + j]];
        keys[t] = tanhf((s + b3[0]) * invd[t]);
    }
    __syncthreads();

    // ================= sortpool rank (jax tie-break: lower index first) ========
    if (t < NPG) {
        float kvv = keys[t];
        int rr = 0;
        #pragma unroll 4
        for (int j = 0; j < NPG; j++) {
            float vj = keys[j];   // broadcast
            rr += ((vj > kvv) || ((vj == kvv) && (j < t))) ? 1 : 0;
        }
        rnk[t] = rr;
    }
    __syncthreads();

    // ================= export selected Z rows (overlay tail on Buf) ===========
    float* sp    = Buf;           // 2910 floats
    float* x1    = Buf + 2910;    // 480
    float* xp    = x1 + 480;      // 240
    float* dense = xp + 240;      // 352  (3982 <= 9252 floats of Buf)

    {
        int r = rnk[n];
        if (r < KTOP) {
            float* dp = sp + r * 97;
            #pragma unroll
            for (int c = 0; c < 16; c++) {
                dp[cb + c]      = a1[c];
                dp[32 + cb + c] = a2[c];
                dp[64 + cb + c] = a3[c];
            }
            if (hh == 0) dp[96] = keys[n];
        }
    }
    __syncthreads();

    // conv1: kernel width 97, stride 97 -> per-row dot; out [16][30], relu
    if (t < 480) {
        int k = t >> 4, c = t & 15;
        float s = cb1[c];
        for (int dd = 0; dd < 97; dd++) s = fmaf(sp[k * 97 + dd], cw1[c * 97 + dd], s);
        x1[c * 30 + k] = fmaxf(s, 0.f);
    }
    __syncthreads();
    // maxpool1d(2,2) -> [16][15]
    if (t < 240) {
        int c = t / 15, k = t - c * 15;
        xp[t] = fmaxf(x1[c * 30 + 2 * k], x1[c * 30 + 2 * k + 1]);
    }
    __syncthreads();
    // conv2: [32][16][5] VALID over 15 -> [32][11], relu; dense idx = c*11+j
    if (t < 352) {
        int c = t / 11, j = t - c * 11;
        float s = cb2[c];
        for (int i2 = 0; i2 < 16; i2++) {
            #pragma unroll
            for (int tt = 0; tt < 5; tt++)
                s = fmaf(xp[i2 * 15 + j + tt], cw2[(c * 16 + i2) * 5 + tt], s);
        }
        dense[t] = fmaxf(s, 0.f);
    }
    __syncthreads();
    // output: relu(relu(dense @ out_w + out_b)) -> [2]
    if (t < 64) {
        float u0 = 0.f, u1 = 0.f;
        for (int dd = t; dd < 352; dd += 64) {
            float v = dense[dd];
            u0 = fmaf(v, ow[dd * 2],     u0);
            u1 = fmaf(v, ow[dd * 2 + 1], u1);
        }
        #pragma unroll
        for (int off2 = 32; off2 > 0; off2 >>= 1) {
            u0 += __shfl_down(u0, off2);
            u1 += __shfl_down(u1, off2);
        }
        if (t == 0) {
            outp[g * 2 + 0] = fmaxf(u0 + ob[0], 0.f);
            outp[g * 2 + 1] = fmaxf(u1 + ob[1], 0.f);
        }
    }
}

extern "C" void kernel_launch(void* const* d_in, const int* in_sizes, int n_in,
                              void* d_out, int out_size, void* d_ws, size_t ws_size,
                              hipStream_t stream) {
    const float* node_feat = (const float*)d_in[0];
    const int*   src       = (const int*)  d_in[1];
    const int*   dst       = (const int*)  d_in[2];
    const int*   degsp     = (const int*)  d_in[3];
    const float* W0 = (const float*)d_in[4];
    const float* b0 = (const float*)d_in[5];
    const float* W1 = (const float*)d_in[6];
    const float* b1 = (const float*)d_in[7];
    const float* W2 = (const float*)d_in[8];
    const float* b2 = (const float*)d_in[9];
    const float* W3 = (const float*)d_in[10];
    const float* b3 = (const float*)d_in[11];
    const float* cw1 = (const float*)d_in[12];
    const float* cb1 = (const float*)d_in[13];
    const float* cw2 = (const float*)d_in[14];
    const float* cb2 = (const float*)d_in[15];
    const float* ow  = (const float*)d_in[16];
    const float* ob  = (const float*)d_in[17];

    dgcnn_fused<<<dim3(256), dim3(NT), 0, stream>>>(
        node_feat, src, dst, degsp,
        W0, b0, W1, b1, W2, b2, W3, b3,
        cw1, cb1, cw2, cb2, ow, ob, (float*)d_out);
}

// Round 7
// 281.927 us; speedup vs baseline: 1.6395x; 1.6395x over previous
//
#include <hip/hip_runtime.h>

#define NPG  256   // nodes per graph
#define EPG  4096  // edges per graph
#define FDIM 128
#define KTOP 30
#define NT   256   // 4 waves, 1/SIMD -- the PROVEN spill-free regime (round 2)
#define RS   36    // row stride (floats): 16B-aligned, bank-even for b128
#define ZROW 256   // zero pad row (degree-divergence padding)

// (256,1): VGPR budget 512/wave -> no spill by construction (round 2: VGPR
// 116, WRITE_SIZE 8KB). NT>=512 blocks made the allocator scratch-place the
// gather working set regardless of launch_bounds / waves_per_eu (rounds 3-6:
// ~900MB scratch traffic, 445-464us). Here we keep NT=256 and instead buy
// speed with b128 LDS access + exactly-even banking + 8-way gather ILP.
__global__ __launch_bounds__(NT, 1)
void dgcnn_fused(const float* __restrict__ node_feat,
                 const int* __restrict__ srcv, const int* __restrict__ dstv,
                 const int* __restrict__ degs,
                 const float* __restrict__ W0, const float* __restrict__ b0,
                 const float* __restrict__ W1, const float* __restrict__ b1,
                 const float* __restrict__ W2, const float* __restrict__ b2,
                 const float* __restrict__ W3, const float* __restrict__ b3,
                 const float* __restrict__ cw1, const float* __restrict__ cb1,
                 const float* __restrict__ cw2, const float* __restrict__ cb2,
                 const float* __restrict__ ow,  const float* __restrict__ ob,
                 float* __restrict__ outp)
{
    __shared__ __attribute__((aligned(16))) float Buf[(NPG + 1) * RS]; // 37008 B
    __shared__ unsigned short srclist[EPG];  // 8192 B; in-edges grouped by dst
    __shared__ int   offs[NPG];
    __shared__ int   cnt [NPG];
    __shared__ int   degl[NPG];
    __shared__ float invd[NPG];
    __shared__ float keys[NPG];
    __shared__ float sbuf[NPG];
    // total ~50.2 KB

    const int g = blockIdx.x;
    const int t = threadIdx.x;

    // ================= degrees + exclusive scan (all 256 threads) =============
    int dn = degs[g * NPG + t];
    degl[t] = dn; cnt[t] = 0;
    invd[t] = 1.0f / (float)(dn + 1);
    offs[t] = dn;
    __syncthreads();
    for (int s = 1; s < NPG; s <<= 1) {
        int v = (t >= s) ? offs[t - s] : 0;
        __syncthreads();
        offs[t] += v;
        __syncthreads();
    }
    offs[t] -= dn;   // exclusive prefix
    if (t < RS) Buf[ZROW * RS + t] = 0.f;   // zero pad row
    __syncthreads();

    // ================= edge-list build (counting sort by dst) =================
    {
        const int4* sg4 = (const int4*)(srcv + g * EPG);
        const int4* dg4 = (const int4*)(dstv + g * EPG);
        #pragma unroll
        for (int i = 0; i < 4; i++) {
            int4 s4 = sg4[t + i * NT];
            int4 d4 = dg4[t + i * NT];
            int ss[4] = {s4.x, s4.y, s4.z, s4.w};
            int dd[4] = {d4.x, d4.y, d4.z, d4.w};
            #pragma unroll
            for (int u = 0; u < 4; u++) {
                int sl = ss[u] & (NPG - 1);   // graphs are 256-node aligned
                int dl = dd[u] & (NPG - 1);
                int p  = atomicAdd(&cnt[dl], 1);
                srclist[offs[dl] + p] = (unsigned short)sl;
            }
        }
    }

    // thread roles
    // node mapping: thread t owns node t (matmuls, archives, keys)
    // gather mapping: 8 lanes x 4ch cover one node-octet's 32 channels
    const int c4  = (t & 7) << 2;   // channel base 0,4,..,28
    const int grp = t >> 3;         // 0..31 node octet
    const int nb  = grp << 3;       // first node of octet

    // ================= phase 0: y0 = X @ W0 (thread = node, 32 out-ch) ========
    float acc[32];
    #pragma unroll
    for (int c = 0; c < 32; c++) acc[c] = 0.f;
    {
        const float* nf = node_feat + (size_t)g * NPG * FDIM;
        for (int kc = 0; kc < 4; kc++) {
            __syncthreads();   // Buf chunk reuse
            #pragma unroll
            for (int i = 0; i < 8; i++) {
                int f  = t + i * NT;          // 0..2047
                int nn = f >> 3, k4 = f & 7;
                float4 v = *(const float4*)(nf + nn * FDIM + kc * 32 + k4 * 4);
                *(float4*)(&Buf[nn * RS + k4 * 4]) = v;   // bank-even b128
            }
            __syncthreads();
            #pragma unroll
            for (int j = 0; j < 8; j++) {
                float4 v = *(const float4*)(&Buf[t * RS + j * 4]);  // even b128
                float rr[4] = {v.x, v.y, v.z, v.w};
                #pragma unroll
                for (int u = 0; u < 4; u++) {
                    const float* wr = W0 + (kc * 32 + j * 4 + u) * 32; // uniform
                    #pragma unroll
                    for (int c = 0; c < 32; c++) acc[c] = fmaf(rr[u], wr[c], acc[c]);
                }
            }
        }
    }
    __syncthreads();
    #pragma unroll
    for (int u = 0; u < 8; u++) {
        float4 v = {acc[u*4], acc[u*4+1], acc[u*4+2], acc[u*4+3]};
        *(float4*)(&Buf[t * RS + u * 4]) = v;   // y0 row (bank-even)
    }
    __syncthreads();

    // per-octet gather state
    int   go[8], gd[8];
    float giv[8];
    #pragma unroll
    for (int i = 0; i < 8; i++) {
        go[i] = offs[nb + i]; gd[i] = degl[nb + i]; giv[i] = invd[nb + i];
    }
    int dm = 0;
    #pragma unroll
    for (int i = 0; i < 8; i++) dm = max(dm, gd[i]);

    // pool[i] = Buf[nb+i][c4..c4+3] + sum_in-edges Buf[src][c4..c4+3]
    // 8 independent chains/thread; each octet's b128s hit all 32 banks evenly.
    auto gather = [&](float4 (&pool)[8]) {
        #pragma unroll
        for (int i = 0; i < 8; i++)
            pool[i] = *(const float4*)(&Buf[(nb + i) * RS + c4]);   // self
        for (int j = 0; j < dm; j++) {
            #pragma unroll
            for (int i = 0; i < 8; i++) {
                int a = ZROW;
                if (j < gd[i]) a = (int)srclist[go[i] + j];
                float4 r = *(const float4*)(&Buf[a * RS + c4]);
                pool[i].x += r.x; pool[i].y += r.y;
                pool[i].z += r.z; pool[i].w += r.w;
            }
        }
    };

    float a1[32], a2[32];   // Z archive (h3 stays in Buf; kv in keys)

    // ---- layer 0: pooled(y0) -> h1 (gather mapping), archive a1 ----
    {
        float4 p[8];
        gather(p);
        float4 bv = *(const float4*)(b0 + c4);
        __syncthreads();   // all gather reads of y0 done
        #pragma unroll
        for (int i = 0; i < 8; i++) {
            float4 hv;
            hv.x = tanhf((p[i].x + bv.x) * giv[i]);
            hv.y = tanhf((p[i].y + bv.y) * giv[i]);
            hv.z = tanhf((p[i].z + bv.z) * giv[i]);
            hv.w = tanhf((p[i].w + bv.w) * giv[i]);
            *(float4*)(&Buf[(nb + i) * RS + c4]) = hv;   // h1
        }
        __syncthreads();
        #pragma unroll
        for (int j = 0; j < 8; j++) {   // capture own h1 row
            float4 v = *(const float4*)(&Buf[t * RS + j * 4]);
            a1[j*4+0] = v.x; a1[j*4+1] = v.y; a1[j*4+2] = v.z; a1[j*4+3] = v.w;
        }
    }

    // ---- layers 1,2: gather pooled -> matmul (node mapping) -> h_next ----
    auto layer = [&](const float* Wn, const float* bn, float (&ar)[32]) {
        float4 p[8];
        gather(p);
        __syncthreads();   // all gather reads done
        #pragma unroll
        for (int i = 0; i < 8; i++)
            *(float4*)(&Buf[(nb + i) * RS + c4]) = p[i];   // pooled rows
        __syncthreads();
        float y[32];
        #pragma unroll
        for (int c = 0; c < 32; c++) y[c] = 0.f;
        #pragma unroll
        for (int j = 0; j < 8; j++) {
            float4 v = *(const float4*)(&Buf[t * RS + j * 4]);  // own pooled row
            float rr[4] = {v.x, v.y, v.z, v.w};
            #pragma unroll
            for (int u = 0; u < 4; u++) {
                const float* wr = Wn + (j * 4 + u) * 32;   // uniform -> s_load
                #pragma unroll
                for (int c = 0; c < 32; c++) y[c] = fmaf(rr[u], wr[c], y[c]);
            }
        }
        float ivn = invd[t];
        #pragma unroll
        for (int c = 0; c < 32; c++) ar[c] = tanhf((y[c] + bn[c]) * ivn);
        __syncthreads();   // all pooled-row reads done
        #pragma unroll
        for (int u = 0; u < 8; u++) {
            float4 v = {ar[u*4], ar[u*4+1], ar[u*4+2], ar[u*4+3]};
            *(float4*)(&Buf[t * RS + u * 4]) = v;   // h_next row
        }
        __syncthreads();
    };
    layer(W1, b1, a2);
    {   // layer 2 -> h3 lives in Buf only (no register archive needed)
        float a3tmp[32];
        layer(W2, b2, a3tmp);
        (void)a3tmp;
    }

    // ---- layer 3: project h3 -> scalar (linearity), pool scalars -> keys ----
    {
        float s = 0.f;
        #pragma unroll
        for (int j = 0; j < 8; j++) {
            float4 v = *(const float4*)(&Buf[t * RS + j * 4]);
            s = fmaf(v.x, W3[j*4+0], s); s = fmaf(v.y, W3[j*4+1], s);
            s = fmaf(v.z, W3[j*4+2], s); s = fmaf(v.w, W3[j*4+3], s);
        }
        sbuf[t] = s;
    }
    __syncthreads();
    float kv;
    {
        float s = sbuf[t];
        int oo = offs[t], d2 = degl[t];
        for (int j = 0; j < d2; j++) s += sbuf[srclist[oo + j]];
        kv = tanhf((s + b3[0]) * invd[t]);
        keys[t] = kv;
    }
    __syncthreads();

    // ================= sortpool rank (jax tie-break: lower index first) ========
    int rank = 0;
    #pragma unroll 4
    for (int j = 0; j < NPG; j++) {
        float vj = keys[j];   // uniform address -> broadcast
        rank += ((vj > kv) || ((vj == kv) && (j < t))) ? 1 : 0;
    }

    // capture h3 for selected rows BEFORE the tail overlay clobbers Buf
    float t3[32];
    if (rank < KTOP) {
        #pragma unroll
        for (int j = 0; j < 8; j++) {
            float4 v = *(const float4*)(&Buf[t * RS + j * 4]);
            t3[j*4+0] = v.x; t3[j*4+1] = v.y; t3[j*4+2] = v.z; t3[j*4+3] = v.w;
        }
    }
    __syncthreads();   // all h3 captures done before overlay writes

    // ================= export selected Z rows (overlay tail on Buf) ===========
    float* sp    = Buf;           // 2910 floats
    float* x1    = Buf + 2910;    // 480
    float* xp    = x1 + 480;      // 240
    float* dense = xp + 240;      // 352  (3982 <= 9252 floats of Buf)

    if (rank < KTOP) {
        float* dp = sp + rank * 97;
        #pragma unroll
        for (int c = 0; c < 32; c++) {
            dp[c]      = a1[c];
            dp[32 + c] = a2[c];
            dp[64 + c] = t3[c];
        }
        dp[96] = kv;
    }
    __syncthreads();

    // conv1: kernel width 97, stride 97 -> per-row dot; out [16][30], relu
    for (int idx = t; idx < 480; idx += NT) {
        int k = idx >> 4, c = idx & 15;
        float s = cb1[c];
        for (int dd = 0; dd < 97; dd++) s = fmaf(sp[k * 97 + dd], cw1[c * 97 + dd], s);
        x1[c * 30 + k] = fmaxf(s, 0.f);
    }
    __syncthreads();
    // maxpool1d(2,2) -> [16][15]
    if (t < 240) {
        int c = t / 15, k = t - c * 15;
        xp[t] = fmaxf(x1[c * 30 + 2 * k], x1[c * 30 + 2 * k + 1]);
    }
    __syncthreads();
    // conv2: [32][16][5] VALID over 15 -> [32][11], relu; dense idx = c*11+j
    for (int idx = t; idx < 352; idx += NT) {
        int c = idx / 11, j = idx - c * 11;
        float s = cb2[c];
        for (int i2 = 0; i2 < 16; i2++) {
            #pragma unroll
            for (int tt = 0; tt < 5; tt++)
                s = fmaf(xp[i2 * 15 + j + tt], cw2[(c * 16 + i2) * 5 + tt], s);
        }
        dense[idx] = fmaxf(s, 0.f);
    }
    __syncthreads();
    // output: relu(relu(dense @ out_w + out_b)) -> [2]
    if (t < 64) {
        float u0 = 0.f, u1 = 0.f;
        for (int dd = t; dd < 352; dd += 64) {
            float v = dense[dd];
            u0 = fmaf(v, ow[dd * 2],     u0);
            u1 = fmaf(v, ow[dd * 2 + 1], u1);
        }
        #pragma unroll
        for (int off2 = 32; off2 > 0; off2 >>= 1) {
            u0 += __shfl_down(u0, off2);
            u1 += __shfl_down(u1, off2);
        }
        if (t == 0) {
            outp[g * 2 + 0] = fmaxf(u0 + ob[0], 0.f);
            outp[g * 2 + 1] = fmaxf(u1 + ob[1], 0.f);
        }
    }
}

extern "C" void kernel_launch(void* const* d_in, const int* in_sizes, int n_in,
                              void* d_out, int out_size, void* d_ws, size_t ws_size,
                              hipStream_t stream) {
    const float* node_feat = (const float*)d_in[0];
    const int*   src       = (const int*)  d_in[1];
    const int*   dst       = (const int*)  d_in[2];
    const int*   degsp     = (const int*)  d_in[3];
    const float* W0 = (const float*)d_in[4];
    const float* b0 = (const float*)d_in[5];
    const float* W1 = (const float*)d_in[6];
    const float* b1 = (const float*)d_in[7];
    const float* W2 = (const float*)d_in[8];
    const float* b2 = (const float*)d_in[9];
    const float* W3 = (const float*)d_in[10];
    const float* b3 = (const float*)d_in[11];
    const float* cw1 = (const float*)d_in[12];
    const float* cb1 = (const float*)d_in[13];
    const float* cw2 = (const float*)d_in[14];
    const float* cb2 = (const float*)d_in[15];
    const float* ow  = (const float*)d_in[16];
    const float* ob  = (const float*)d_in[17];

    dgcnn_fused<<<dim3(256), dim3(NT), 0, stream>>>(
        node_feat, src, dst, degsp,
        W0, b0, W1, b1, W2, b2, W3, b3,
        cw1, cb1, cw2, cb2, ow, ob, (float*)d_out);
}